// Round 13
// baseline (223.285 us; speedup 1.0000x reference)
//
#include <hip/hip_runtime.h>
#include <hip/hip_bf16.h>

typedef __attribute__((ext_vector_type(8))) short bf16x8;
typedef __attribute__((ext_vector_type(4))) float f32x4;

#define SCALE_F 0.17677669529663687f
#define LOG2E_F 1.4426950408889634f
#define SCALEL_F (0.17677669529663687f * 1.4426950408889634f)

__device__ __forceinline__ unsigned short f2bf(float f) {
    union { float f; unsigned int u; } v; v.f = f;
    unsigned int r = v.u + 0x7FFFu + ((v.u >> 16) & 1u);
    return (unsigned short)(r >> 16);
}

// HW-converted pack via __float2bfloat16 (ROCm 7.2 has no __floats2bfloat162_rn).
__device__ __forceinline__ unsigned pack2(float lo, float hi) {
    __hip_bfloat16 a = __float2bfloat16(lo);
    __hip_bfloat16 b = __float2bfloat16(hi);
    unsigned short ua, ub;
    __builtin_memcpy(&ua, &a, 2);
    __builtin_memcpy(&ub, &b, 2);
    return (unsigned)ua | ((unsigned)ub << 16);
}

__device__ __forceinline__ bf16x8 build8(unsigned u0, unsigned u1, unsigned u2, unsigned u3) {
    bf16x8 vv;
    vv[0] = (short)(u0 & 0xffffu); vv[1] = (short)(u0 >> 16);
    vv[2] = (short)(u1 & 0xffffu); vv[3] = (short)(u1 >> 16);
    vv[4] = (short)(u2 & 0xffffu); vv[5] = (short)(u2 >> 16);
    vv[6] = (short)(u3 & 0xffffu); vv[7] = (short)(u3 >> 16);
    return vv;
}

// Linear XOR swizzle (row bits folded into 16B-block bits).
__device__ __forceinline__ int swzm(int row) {
    return ((row & 1) << 4)
         ^ ((((row >> 1) ^ (row >> 2)) & 1) << 5)
         ^ ((((row >> 2) ^ (row >> 3)) & 1) << 6);
}
__device__ __forceinline__ int swzA(int row, int col) {   // 512-B rows
    return (((row << 9) + (col << 1)) ^ swzm(row));
}

// ---------------- prep kernels ----------------
extern "C" __global__ void prep_gbs_k(const float* __restrict__ emb,
                                      const float* __restrict__ pw,
                                      float* __restrict__ gbs) {
    int i = blockIdx.x * 256 + threadIdx.x;      // 8*768
    if (i >= 8 * 768) return;
    int b = i / 768, o = i - b * 768;
    const float* e = emb + b * 512;
    const float* wr = pw + o * 512;
    float s = 0.f;
    for (int k = 0; k < 512; k += 4) {
        float4 ev = *(const float4*)(e + k);
        float4 wv = *(const float4*)(wr + k);
        s += ev.x * wv.x + ev.y * wv.y + ev.z * wv.z + ev.w * wv.w;
    }
    gbs[i] = s;
}

extern "C" __global__ void prep_w_k(const float* __restrict__ wq, const float* __restrict__ wk,
                                    const float* __restrict__ wv, const float* __restrict__ wo,
                                    unsigned short* __restrict__ dst) {
    int i = blockIdx.x * 256 + threadIdx.x;
    int sel = i >> 14;
    const float* s = (sel == 0) ? wq : (sel == 1) ? wk : (sel == 2) ? wv : wo;
    float4 v = *(const float4*)(s + (i & 16383) * 4);
    ushort4 p;
    p.x = f2bf(v.x); p.y = f2bf(v.y); p.z = f2bf(v.z); p.w = f2bf(v.w);
    *(ushort4*)(dst + i * 4) = p;
}

// bias premultiplied by LOG2E so the softmax uses exp2 directly
extern "C" __global__ void prep_bias_k(const float* __restrict__ bt, float* __restrict__ bp) {
    int i = blockIdx.x * 256 + threadIdx.x;      // 8*64*64  [h][i][j]
    int h = i >> 12, r = (i >> 6) & 63, cc = i & 63;
    float v;
    if (cc >= 49) v = -1e30f;
    else if (r >= 49) v = 0.f;
    else {
        int ri = r / 7, ci = r - ri * 7, rj = cc / 7, cj = cc - rj * 7;
        int rel = (ri - rj + 6) * 13 + (ci - cj + 6);
        v = bt[rel * 8 + h];
    }
    bp[i] = v * LOG2E_F;
}

// ---------------- main fused kernel ----------------
// grid 2048, 256 threads (4 waves; wave w = heads 2w, 2w+1 sequential).
// LDS = xm only (25.6 KiB). Q, K, V, P all in registers (shuffle redist).
// Register model (r4-r11, verified): waves/SIMD = floor(256/VGPR); caps below
// the ~110-140 natural live-state cause catastrophic scratch spills. (256,2)
// caps at 128 -> 2 blocks/CU = 8 waves/CU spill-free (r11: FETCH 59.9 MB).
// r13: VALU-stream reduction (HW cvt packs, LOG2E folded into bias,
// deferred 1/sum) — structure otherwise identical to the passing r11.
extern "C" __global__ void __launch_bounds__(256, 2)
attn_main(const float* __restrict__ x,
          const float* __restrict__ lnw, const float* __restrict__ lnb,
          const unsigned short* __restrict__ wqb, const unsigned short* __restrict__ wkb,
          const unsigned short* __restrict__ wvb, const unsigned short* __restrict__ wob,
          const float* __restrict__ gbs, const float* __restrict__ bpad,
          float* __restrict__ out)
{
    __shared__ char lds[25600];
    const int tid = threadIdx.x;
    const int w = tid >> 6;          // wave 0..3
    const int l = tid & 63;
    const int g = l >> 4;
    const int c = l & 15;
    const int win = blockIdx.x;
    const int bb = win >> 8;
    const f32x4 z4 = {0.f, 0.f, 0.f, 0.f};
    const bf16x8 z8 = {0, 0, 0, 0, 0, 0, 0, 0};
    // shuffle-redistribution lanes (validated r4-r11)
    const int srcA = ((l >> 4) & 1) * 32 + (l & 15);
    const int srcB = srcA + 16;
    const bool hi2 = (g >= 2);
    const bool hiSel = (l >= 32);

    // ---- AdaLayerNorm -> xm rows 0..48 (+ zero row 49) ----
    {
        float4 lnw4 = *(const float4*)(lnw + 4 * l);
        float4 lnb4 = *(const float4*)(lnb + 4 * l);
        float4 gam4 = *(const float4*)(gbs + bb * 768 + 4 * l);
        float4 bet4 = *(const float4*)(gbs + bb * 768 + 256 + 4 * l);
        for (int t = w; t < 49; t += 4) {
            float4 v = *(const float4*)(x + ((size_t)win * 49 + t) * 256 + 4 * l);
            float s = v.x + v.y + v.z + v.w;
            float ss = v.x * v.x + v.y * v.y + v.z * v.z + v.w * v.w;
            #pragma unroll
            for (int off = 32; off >= 1; off >>= 1) {
                s += __shfl_xor(s, off);
                ss += __shfl_xor(ss, off);
            }
            float mu = s * (1.0f / 256.0f);
            float var = ss * (1.0f / 256.0f) - mu * mu;
            float rstd = rsqrtf(var + 1e-5f);
            uint2 p;
            p.x = pack2(((v.x - mu) * rstd * lnw4.x + lnb4.x) * (1.0f + gam4.x) + bet4.x,
                        ((v.y - mu) * rstd * lnw4.y + lnb4.y) * (1.0f + gam4.y) + bet4.y);
            p.y = pack2(((v.z - mu) * rstd * lnw4.z + lnb4.z) * (1.0f + gam4.z) + bet4.z,
                        ((v.w - mu) * rstd * lnw4.w + lnb4.w) * (1.0f + gam4.w) + bet4.w);
            *(uint2*)(lds + swzA(t, 4 * l)) = p;
        }
        if (w == 3) {
            uint2 zp; zp.x = 0; zp.y = 0;
            *(uint2*)(lds + swzA(49, 4 * l)) = zp;
        }
    }
    __syncthreads();     // bar1: xm ready

    unsigned oPk[2][2][4][2];    // packed attn-out [hh][dt][it][half]

    #pragma unroll
    for (int hh = 0; hh < 2; ++hh) {
        const int h = 2 * w + hh;

        // ---- Q + K projections (swapped), shared xm B-frags -> qf/kf regs ----
        bf16x8 qf[4], kf[4];
        {
            f32x4 aq[2][4], ak[2][4];
            #pragma unroll
            for (int dt = 0; dt < 2; ++dt)
                #pragma unroll
                for (int tt = 0; tt < 4; ++tt) { aq[dt][tt] = z4; ak[dt][tt] = z4; }
            #pragma unroll
            for (int kt = 0; kt < 8; ++kt) {
                const int ko = kt * 32 + g * 8;
                bf16x8 b0 = *(const bf16x8*)(lds + swzA(c, ko));
                bf16x8 b1 = *(const bf16x8*)(lds + swzA(16 + c, ko));
                bf16x8 b2 = *(const bf16x8*)(lds + swzA(32 + c, ko));
                bf16x8 b3 = z8; if (c < 2) b3 = *(const bf16x8*)(lds + swzA(48 + c, ko));
                bf16x8 wq0 = *(const bf16x8*)(wqb + (h * 32 + c) * 256 + ko);
                bf16x8 wq1 = *(const bf16x8*)(wqb + (h * 32 + 16 + c) * 256 + ko);
                bf16x8 wk0 = *(const bf16x8*)(wkb + (h * 32 + c) * 256 + ko);
                bf16x8 wk1 = *(const bf16x8*)(wkb + (h * 32 + 16 + c) * 256 + ko);
                aq[0][0] = __builtin_amdgcn_mfma_f32_16x16x32_bf16(wq0, b0, aq[0][0], 0, 0, 0);
                aq[0][1] = __builtin_amdgcn_mfma_f32_16x16x32_bf16(wq0, b1, aq[0][1], 0, 0, 0);
                aq[0][2] = __builtin_amdgcn_mfma_f32_16x16x32_bf16(wq0, b2, aq[0][2], 0, 0, 0);
                aq[0][3] = __builtin_amdgcn_mfma_f32_16x16x32_bf16(wq0, b3, aq[0][3], 0, 0, 0);
                aq[1][0] = __builtin_amdgcn_mfma_f32_16x16x32_bf16(wq1, b0, aq[1][0], 0, 0, 0);
                aq[1][1] = __builtin_amdgcn_mfma_f32_16x16x32_bf16(wq1, b1, aq[1][1], 0, 0, 0);
                aq[1][2] = __builtin_amdgcn_mfma_f32_16x16x32_bf16(wq1, b2, aq[1][2], 0, 0, 0);
                aq[1][3] = __builtin_amdgcn_mfma_f32_16x16x32_bf16(wq1, b3, aq[1][3], 0, 0, 0);
                ak[0][0] = __builtin_amdgcn_mfma_f32_16x16x32_bf16(wk0, b0, ak[0][0], 0, 0, 0);
                ak[0][1] = __builtin_amdgcn_mfma_f32_16x16x32_bf16(wk0, b1, ak[0][1], 0, 0, 0);
                ak[0][2] = __builtin_amdgcn_mfma_f32_16x16x32_bf16(wk0, b2, ak[0][2], 0, 0, 0);
                ak[0][3] = __builtin_amdgcn_mfma_f32_16x16x32_bf16(wk0, b3, ak[0][3], 0, 0, 0);
                ak[1][0] = __builtin_amdgcn_mfma_f32_16x16x32_bf16(wk1, b0, ak[1][0], 0, 0, 0);
                ak[1][1] = __builtin_amdgcn_mfma_f32_16x16x32_bf16(wk1, b1, ak[1][1], 0, 0, 0);
                ak[1][2] = __builtin_amdgcn_mfma_f32_16x16x32_bf16(wk1, b2, ak[1][2], 0, 0, 0);
                ak[1][3] = __builtin_amdgcn_mfma_f32_16x16x32_bf16(wk1, b3, ak[1][3], 0, 0, 0);
            }
            unsigned qA[2][4], qB[2][4], kA[2][4], kB[2][4];
            #pragma unroll
            for (int dt = 0; dt < 2; ++dt)
                #pragma unroll
                for (int tt = 0; tt < 4; ++tt) {
                    qA[dt][tt] = pack2(aq[dt][tt][0], aq[dt][tt][1]);
                    qB[dt][tt] = pack2(aq[dt][tt][2], aq[dt][tt][3]);
                    kA[dt][tt] = pack2(ak[dt][tt][0], ak[dt][tt][1]);
                    kB[dt][tt] = pack2(ak[dt][tt][2], ak[dt][tt][3]);
                }
            #pragma unroll
            for (int it = 0; it < 4; ++it) {
                unsigned a0 = (unsigned)__shfl((int)qA[0][it], srcA);
                unsigned a1 = (unsigned)__shfl((int)qA[1][it], srcA);
                unsigned b0 = (unsigned)__shfl((int)qB[0][it], srcA);
                unsigned b1 = (unsigned)__shfl((int)qB[1][it], srcA);
                unsigned c0 = (unsigned)__shfl((int)qA[0][it], srcB);
                unsigned c1 = (unsigned)__shfl((int)qA[1][it], srcB);
                unsigned d0 = (unsigned)__shfl((int)qB[0][it], srcB);
                unsigned d1 = (unsigned)__shfl((int)qB[1][it], srcB);
                qf[it] = build8(hi2 ? a1 : a0, hi2 ? b1 : b0, hi2 ? c1 : c0, hi2 ? d1 : d0);
                a0 = (unsigned)__shfl((int)kA[0][it], srcA);
                a1 = (unsigned)__shfl((int)kA[1][it], srcA);
                b0 = (unsigned)__shfl((int)kB[0][it], srcA);
                b1 = (unsigned)__shfl((int)kB[1][it], srcA);
                c0 = (unsigned)__shfl((int)kA[0][it], srcB);
                c1 = (unsigned)__shfl((int)kA[1][it], srcB);
                d0 = (unsigned)__shfl((int)kB[0][it], srcB);
                d1 = (unsigned)__shfl((int)kB[1][it], srcB);
                kf[it] = build8(hi2 ? a1 : a0, hi2 ? b1 : b0, hi2 ? c1 : c0, hi2 ? d1 : d0);
            }
        }

        // ---- QK^T (swapped, all-reg) + softmax (unnorm) + in-reg P redist ----
        bf16x8 pv[4][2];
        float ivs[4];
        #pragma unroll
        for (int it = 0; it < 4; ++it) {
            f32x4 s0 = __builtin_amdgcn_mfma_f32_16x16x32_bf16(kf[0], qf[it], z4, 0, 0, 0);
            f32x4 s1 = __builtin_amdgcn_mfma_f32_16x16x32_bf16(kf[1], qf[it], z4, 0, 0, 0);
            f32x4 s2 = __builtin_amdgcn_mfma_f32_16x16x32_bf16(kf[2], qf[it], z4, 0, 0, 0);
            f32x4 s3 = __builtin_amdgcn_mfma_f32_16x16x32_bf16(kf[3], qf[it], z4, 0, 0, 0);
            const float* bp = bpad + h * 4096 + (it * 16 + c) * 64 + 4 * g;
            float4 B0 = *(const float4*)(bp);
            float4 B1 = *(const float4*)(bp + 16);
            float4 B2 = *(const float4*)(bp + 32);
            float4 B3 = *(const float4*)(bp + 48);
            s0[0] = s0[0] * SCALEL_F + B0.x; s0[1] = s0[1] * SCALEL_F + B0.y;
            s0[2] = s0[2] * SCALEL_F + B0.z; s0[3] = s0[3] * SCALEL_F + B0.w;
            s1[0] = s1[0] * SCALEL_F + B1.x; s1[1] = s1[1] * SCALEL_F + B1.y;
            s1[2] = s1[2] * SCALEL_F + B1.z; s1[3] = s1[3] * SCALEL_F + B1.w;
            s2[0] = s2[0] * SCALEL_F + B2.x; s2[1] = s2[1] * SCALEL_F + B2.y;
            s2[2] = s2[2] * SCALEL_F + B2.z; s2[3] = s2[3] * SCALEL_F + B2.w;
            s3[0] = s3[0] * SCALEL_F + B3.x; s3[1] = s3[1] * SCALEL_F + B3.y;
            s3[2] = s3[2] * SCALEL_F + B3.z; s3[3] = s3[3] * SCALEL_F + B3.w;
            float mm = fmaxf(fmaxf(fmaxf(s0[0], s0[1]), fmaxf(s0[2], s0[3])),
                       fmaxf(fmaxf(fmaxf(s1[0], s1[1]), fmaxf(s1[2], s1[3])),
                       fmaxf(fmaxf(fmaxf(s2[0], s2[1]), fmaxf(s2[2], s2[3])),
                             fmaxf(fmaxf(s3[0], s3[1]), fmaxf(s3[2], s3[3])))));
            mm = fmaxf(mm, __shfl_xor(mm, 16));
            mm = fmaxf(mm, __shfl_xor(mm, 32));
            #pragma unroll
            for (int r = 0; r < 4; ++r) {
                s0[r] = exp2f(s0[r] - mm);
                s1[r] = exp2f(s1[r] - mm);
                s2[r] = exp2f(s2[r] - mm);
                s3[r] = exp2f(s3[r] - mm);
            }
            float ss = (s0[0] + s0[1] + s0[2] + s0[3]) + (s1[0] + s1[1] + s1[2] + s1[3])
                     + (s2[0] + s2[1] + s2[2] + s2[3]) + (s3[0] + s3[1] + s3[2] + s3[3]);
            ss += __shfl_xor(ss, 16);
            ss += __shfl_xor(ss, 32);
            ivs[it] = 1.0f / ss;
            unsigned pkt[4][2];
            pkt[0][0] = pack2(s0[0], s0[1]); pkt[0][1] = pack2(s0[2], s0[3]);
            pkt[1][0] = pack2(s1[0], s1[1]); pkt[1][1] = pack2(s1[2], s1[3]);
            pkt[2][0] = pack2(s2[0], s2[1]); pkt[2][1] = pack2(s2[2], s2[3]);
            pkt[3][0] = pack2(s3[0], s3[1]); pkt[3][1] = pack2(s3[2], s3[3]);
            #pragma unroll
            for (int kt = 0; kt < 2; ++kt) {
                unsigned x0, x1, u0, u1, u2, u3;
                x0 = (unsigned)__shfl((int)pkt[2 * kt][0], srcA);
                x1 = (unsigned)__shfl((int)pkt[2 * kt + 1][0], srcA);
                u0 = hiSel ? x1 : x0;
                x0 = (unsigned)__shfl((int)pkt[2 * kt][1], srcA);
                x1 = (unsigned)__shfl((int)pkt[2 * kt + 1][1], srcA);
                u1 = hiSel ? x1 : x0;
                x0 = (unsigned)__shfl((int)pkt[2 * kt][0], srcB);
                x1 = (unsigned)__shfl((int)pkt[2 * kt + 1][0], srcB);
                u2 = hiSel ? x1 : x0;
                x0 = (unsigned)__shfl((int)pkt[2 * kt][1], srcB);
                x1 = (unsigned)__shfl((int)pkt[2 * kt + 1][1], srcB);
                u3 = hiSel ? x1 : x0;
                pv[it][kt] = build8(u0, u1, u2, u3);
            }
        }

        // ---- V projection (unswapped, shared B-frags) -> va regs ----
        bf16x8 va[2][2];
        {
            f32x4 acc[2][4];
            #pragma unroll
            for (int cti = 0; cti < 2; ++cti)
                #pragma unroll
                for (int tt = 0; tt < 4; ++tt) acc[cti][tt] = z4;
            #pragma unroll
            for (int kt = 0; kt < 8; ++kt) {
                const int ko = kt * 32 + g * 8;
                bf16x8 a0 = *(const bf16x8*)(lds + swzA(c, ko));
                bf16x8 a1 = *(const bf16x8*)(lds + swzA(16 + c, ko));
                bf16x8 a2 = *(const bf16x8*)(lds + swzA(32 + c, ko));
                bf16x8 a3 = z8; if (c < 2) a3 = *(const bf16x8*)(lds + swzA(48 + c, ko));
                bf16x8 b0 = *(const bf16x8*)(wvb + (h * 32 + c) * 256 + ko);
                bf16x8 b1 = *(const bf16x8*)(wvb + (h * 32 + 16 + c) * 256 + ko);
                acc[0][0] = __builtin_amdgcn_mfma_f32_16x16x32_bf16(a0, b0, acc[0][0], 0, 0, 0);
                acc[0][1] = __builtin_amdgcn_mfma_f32_16x16x32_bf16(a1, b0, acc[0][1], 0, 0, 0);
                acc[0][2] = __builtin_amdgcn_mfma_f32_16x16x32_bf16(a2, b0, acc[0][2], 0, 0, 0);
                acc[0][3] = __builtin_amdgcn_mfma_f32_16x16x32_bf16(a3, b0, acc[0][3], 0, 0, 0);
                acc[1][0] = __builtin_amdgcn_mfma_f32_16x16x32_bf16(a0, b1, acc[1][0], 0, 0, 0);
                acc[1][1] = __builtin_amdgcn_mfma_f32_16x16x32_bf16(a1, b1, acc[1][1], 0, 0, 0);
                acc[1][2] = __builtin_amdgcn_mfma_f32_16x16x32_bf16(a2, b1, acc[1][2], 0, 0, 0);
                acc[1][3] = __builtin_amdgcn_mfma_f32_16x16x32_bf16(a3, b1, acc[1][3], 0, 0, 0);
            }
            unsigned vA[2][4], vB[2][4];
            #pragma unroll
            for (int cti = 0; cti < 2; ++cti)
                #pragma unroll
                for (int tt = 0; tt < 4; ++tt) {
                    vA[cti][tt] = pack2(acc[cti][tt][0], acc[cti][tt][1]);
                    vB[cti][tt] = pack2(acc[cti][tt][2], acc[cti][tt][3]);
                }
            #pragma unroll
            for (int dt = 0; dt < 2; ++dt)
                #pragma unroll
                for (int kt = 0; kt < 2; ++kt) {
                    unsigned a0 = (unsigned)__shfl((int)vA[dt][2 * kt],     srcA);
                    unsigned a1 = (unsigned)__shfl((int)vA[dt][2 * kt + 1], srcA);
                    unsigned b0 = (unsigned)__shfl((int)vB[dt][2 * kt],     srcA);
                    unsigned b1 = (unsigned)__shfl((int)vB[dt][2 * kt + 1], srcA);
                    unsigned c0 = (unsigned)__shfl((int)vA[dt][2 * kt],     srcB);
                    unsigned c1 = (unsigned)__shfl((int)vA[dt][2 * kt + 1], srcB);
                    unsigned d0 = (unsigned)__shfl((int)vB[dt][2 * kt],     srcB);
                    unsigned d1 = (unsigned)__shfl((int)vB[dt][2 * kt + 1], srcB);
                    va[dt][kt] = build8(hi2 ? a1 : a0, hi2 ? b1 : b0, hi2 ? c1 : c0, hi2 ? d1 : d0);
                }
        }

        // ---- PV -> packed attn-out regs (apply deferred 1/sum here) ----
        #pragma unroll
        for (int dt = 0; dt < 2; ++dt) {
            f32x4 o[4] = {z4, z4, z4, z4};
            #pragma unroll
            for (int kt = 0; kt < 2; ++kt)
                #pragma unroll
                for (int it = 0; it < 4; ++it)
                    o[it] = __builtin_amdgcn_mfma_f32_16x16x32_bf16(va[dt][kt], pv[it][kt], o[it], 0, 0, 0);
            #pragma unroll
            for (int it = 0; it < 4; ++it) {
                oPk[hh][dt][it][0] = pack2(o[it][0] * ivs[it], o[it][1] * ivs[it]);
                oPk[hh][dt][it][1] = pack2(o[it][2] * ivs[it], o[it][3] * ivs[it]);
            }
        }
    }
    __syncthreads();     // bar2: all xm reads done -> attn-out may overwrite xm

    // ---- dump packed attn-out -> xm region ----
    #pragma unroll
    for (int hh = 0; hh < 2; ++hh)
        #pragma unroll
        for (int dt = 0; dt < 2; ++dt)
            #pragma unroll
            for (int it = 0; it < 4; ++it)
                if (it < 3 || c < 2) {
                    uint2 u;
                    u.x = oPk[hh][dt][it][0];
                    u.y = oPk[hh][dt][it][1];
                    *(uint2*)(lds + swzA(it * 16 + c, (2 * w + hh) * 32 + dt * 16 + 4 * g)) = u;
                }
    __syncthreads();     // bar3: attn-out ready

    // ---- O projection (swapped, two qp-passes, acc=32) + sigma gate ----
    #pragma unroll
    for (int qp = 0; qp < 2; ++qp) {
        f32x4 acc[2][4];
        #pragma unroll
        for (int qq = 0; qq < 2; ++qq)
            #pragma unroll
            for (int tt = 0; tt < 4; ++tt) acc[qq][tt] = z4;
        #pragma unroll
        for (int kt = 0; kt < 8; ++kt) {
            const int ko = kt * 32 + g * 8;
            bf16x8 b0 = *(const bf16x8*)(lds + swzA(c, ko));
            bf16x8 b1 = *(const bf16x8*)(lds + swzA(16 + c, ko));
            bf16x8 b2 = *(const bf16x8*)(lds + swzA(32 + c, ko));
            bf16x8 b3 = z8; if (c < 2) b3 = *(const bf16x8*)(lds + swzA(48 + c, ko));
            bf16x8 a0 = *(const bf16x8*)(wob + (w * 64 + qp * 32 + c) * 256 + ko);
            bf16x8 a1 = *(const bf16x8*)(wob + (w * 64 + qp * 32 + 16 + c) * 256 + ko);
            acc[0][0] = __builtin_amdgcn_mfma_f32_16x16x32_bf16(a0, b0, acc[0][0], 0, 0, 0);
            acc[0][1] = __builtin_amdgcn_mfma_f32_16x16x32_bf16(a0, b1, acc[0][1], 0, 0, 0);
            acc[0][2] = __builtin_amdgcn_mfma_f32_16x16x32_bf16(a0, b2, acc[0][2], 0, 0, 0);
            acc[0][3] = __builtin_amdgcn_mfma_f32_16x16x32_bf16(a0, b3, acc[0][3], 0, 0, 0);
            acc[1][0] = __builtin_amdgcn_mfma_f32_16x16x32_bf16(a1, b0, acc[1][0], 0, 0, 0);
            acc[1][1] = __builtin_amdgcn_mfma_f32_16x16x32_bf16(a1, b1, acc[1][1], 0, 0, 0);
            acc[1][2] = __builtin_amdgcn_mfma_f32_16x16x32_bf16(a1, b2, acc[1][2], 0, 0, 0);
            acc[1][3] = __builtin_amdgcn_mfma_f32_16x16x32_bf16(a1, b3, acc[1][3], 0, 0, 0);
        }
        #pragma unroll
        for (int qq = 0; qq < 2; ++qq) {
            const int col = w * 64 + qp * 32 + qq * 16 + 4 * g;
            float4 sg = *(const float4*)(gbs + bb * 768 + 512 + col);
            #pragma unroll
            for (int tt = 0; tt < 4; ++tt) {
                int tok = tt * 16 + c;
                if (tok < 49) {
                    float4 o4;
                    o4.x = acc[qq][tt][0] * sg.x;
                    o4.y = acc[qq][tt][1] * sg.y;
                    o4.z = acc[qq][tt][2] * sg.z;
                    o4.w = acc[qq][tt][3] * sg.w;
                    *(float4*)(out + ((size_t)win * 49 + tok) * 256 + col) = o4;
                }
            }
        }
    }
}

extern "C" void kernel_launch(void* const* d_in, const int* in_sizes, int n_in,
                              void* d_out, int out_size, void* d_ws, size_t ws_size,
                              hipStream_t stream) {
    (void)in_sizes; (void)n_in; (void)out_size; (void)ws_size;
    const float* x   = (const float*)d_in[0];
    const float* emb = (const float*)d_in[1];
    const float* lnw = (const float*)d_in[2];
    const float* lnb = (const float*)d_in[3];
    const float* pw  = (const float*)d_in[4];
    const float* wq  = (const float*)d_in[5];
    const float* wk  = (const float*)d_in[6];
    const float* wv  = (const float*)d_in[7];
    const float* wo  = (const float*)d_in[8];
    const float* bt  = (const float*)d_in[9];
    float* out = (float*)d_out;

    char* ws = (char*)d_ws;
    float* gbs = (float*)ws;                                   // 24576 B
    unsigned short* wb = (unsigned short*)(ws + 24576);        // 524288 B
    float* biasp = (float*)(ws + 24576 + 524288);              // 131072 B

    prep_gbs_k<<<24, 256, 0, stream>>>(emb, pw, gbs);
    prep_w_k<<<256, 256, 0, stream>>>(wq, wk, wv, wo, wb);
    prep_bias_k<<<128, 256, 0, stream>>>(bt, biasp);
    attn_main<<<2048, 256, 0, stream>>>(x, lnw, lnb,
                                        wb, wb + 65536, wb + 131072, wb + 196608,
                                        gbs, biasp, out);
}

// Round 16
// 220.338 us; speedup vs baseline: 1.0134x; 1.0134x over previous
//
#include <hip/hip_runtime.h>

typedef __attribute__((ext_vector_type(8))) short bf16x8;
typedef __attribute__((ext_vector_type(4))) float f32x4;

#define SCALE_F 0.17677669529663687f
#define LOG2E_F 1.4426950408889634f

__device__ __forceinline__ unsigned short f2bf(float f) {
    union { float f; unsigned int u; } v; v.f = f;
    unsigned int r = v.u + 0x7FFFu + ((v.u >> 16) & 1u);
    return (unsigned short)(r >> 16);
}

__device__ __forceinline__ unsigned pack2(float lo, float hi) {
    return (unsigned)f2bf(lo) | ((unsigned)f2bf(hi) << 16);
}

__device__ __forceinline__ bf16x8 build8(unsigned u0, unsigned u1, unsigned u2, unsigned u3) {
    bf16x8 vv;
    vv[0] = (short)(u0 & 0xffffu); vv[1] = (short)(u0 >> 16);
    vv[2] = (short)(u1 & 0xffffu); vv[3] = (short)(u1 >> 16);
    vv[4] = (short)(u2 & 0xffffu); vv[5] = (short)(u2 >> 16);
    vv[6] = (short)(u3 & 0xffffu); vv[7] = (short)(u3 >> 16);
    return vv;
}

// Linear XOR swizzle (row bits folded into 16B-block bits).
__device__ __forceinline__ int swzm(int row) {
    return ((row & 1) << 4)
         ^ ((((row >> 1) ^ (row >> 2)) & 1) << 5)
         ^ ((((row >> 2) ^ (row >> 3)) & 1) << 6);
}
__device__ __forceinline__ int swzA(int row, int col) {   // 512-B rows
    return (((row << 9) + (col << 1)) ^ swzm(row));
}

// ---------------- prep kernels ----------------
extern "C" __global__ void prep_gbs_k(const float* __restrict__ emb,
                                      const float* __restrict__ pw,
                                      float* __restrict__ gbs) {
    int i = blockIdx.x * 256 + threadIdx.x;      // 8*768
    if (i >= 8 * 768) return;
    int b = i / 768, o = i - b * 768;
    const float* e = emb + b * 512;
    const float* wr = pw + o * 512;
    float s = 0.f;
    for (int k = 0; k < 512; k += 4) {
        float4 ev = *(const float4*)(e + k);
        float4 wv = *(const float4*)(wr + k);
        s += ev.x * wv.x + ev.y * wv.y + ev.z * wv.z + ev.w * wv.w;
    }
    gbs[i] = s;
}

extern "C" __global__ void prep_w_k(const float* __restrict__ wq, const float* __restrict__ wk,
                                    const float* __restrict__ wv, const float* __restrict__ wo,
                                    unsigned short* __restrict__ dst) {
    int i = blockIdx.x * 256 + threadIdx.x;
    int sel = i >> 14;
    const float* s = (sel == 0) ? wq : (sel == 1) ? wk : (sel == 2) ? wv : wo;
    float4 v = *(const float4*)(s + (i & 16383) * 4);
    ushort4 p;
    p.x = f2bf(v.x); p.y = f2bf(v.y); p.z = f2bf(v.z); p.w = f2bf(v.w);
    *(ushort4*)(dst + i * 4) = p;
}

extern "C" __global__ void prep_bias_k(const float* __restrict__ bt, float* __restrict__ bp) {
    int i = blockIdx.x * 256 + threadIdx.x;      // 8*64*64  [h][i][j]
    int h = i >> 12, r = (i >> 6) & 63, cc = i & 63;
    float v;
    if (cc >= 49) v = -1e30f;
    else if (r >= 49) v = 0.f;
    else {
        int ri = r / 7, ci = r - ri * 7, rj = cc / 7, cj = cc - rj * 7;
        int rel = (ri - rj + 6) * 13 + (ci - cj + 6);
        v = bt[rel * 8 + h];
    }
    bp[i] = v;
}

// ---------------- main fused kernel (r11 — verified best, byte-exact) ----------------
// grid 2048, 256 threads (4 waves; wave w = heads 2w, 2w+1 sequential).
// LDS = xm only (25.6 KiB). Q, K, V, P all in registers (shuffle redist).
// Register model (r4-r10, verified): effective budget 256 regs/wave; caps below
// the ~110-140 natural live-state cause catastrophic scratch spills. (256,2)
// caps at 128 -> 2 blocks/CU = 8 waves/CU spill-free (r11: FETCH 59.9 MB,
// dur 244 us, absmax 0.1328).
extern "C" __global__ void __launch_bounds__(256, 2)
attn_main(const float* __restrict__ x,
          const float* __restrict__ lnw, const float* __restrict__ lnb,
          const unsigned short* __restrict__ wqb, const unsigned short* __restrict__ wkb,
          const unsigned short* __restrict__ wvb, const unsigned short* __restrict__ wob,
          const float* __restrict__ gbs, const float* __restrict__ bpad,
          float* __restrict__ out)
{
    __shared__ char lds[25600];
    const int tid = threadIdx.x;
    const int w = tid >> 6;          // wave 0..3
    const int l = tid & 63;
    const int g = l >> 4;
    const int c = l & 15;
    const int win = blockIdx.x;
    const int bb = win >> 8;
    const f32x4 z4 = {0.f, 0.f, 0.f, 0.f};
    const bf16x8 z8 = {0, 0, 0, 0, 0, 0, 0, 0};
    const int srcA = ((l >> 4) & 1) * 32 + (l & 15);
    const int srcB = srcA + 16;
    const bool hi2 = (g >= 2);
    const bool hiSel = (l >= 32);

    // ---- AdaLayerNorm -> xm rows 0..48 (+ zero row 49) ----
    {
        float4 lnw4 = *(const float4*)(lnw + 4 * l);
        float4 lnb4 = *(const float4*)(lnb + 4 * l);
        float4 gam4 = *(const float4*)(gbs + bb * 768 + 4 * l);
        float4 bet4 = *(const float4*)(gbs + bb * 768 + 256 + 4 * l);
        for (int t = w; t < 49; t += 4) {
            float4 v = *(const float4*)(x + ((size_t)win * 49 + t) * 256 + 4 * l);
            float s = v.x + v.y + v.z + v.w;
            float ss = v.x * v.x + v.y * v.y + v.z * v.z + v.w * v.w;
            #pragma unroll
            for (int off = 32; off >= 1; off >>= 1) {
                s += __shfl_xor(s, off);
                ss += __shfl_xor(ss, off);
            }
            float mu = s * (1.0f / 256.0f);
            float var = ss * (1.0f / 256.0f) - mu * mu;
            float rstd = rsqrtf(var + 1e-5f);
            ushort4 p;
            p.x = f2bf(((v.x - mu) * rstd * lnw4.x + lnb4.x) * (1.0f + gam4.x) + bet4.x);
            p.y = f2bf(((v.y - mu) * rstd * lnw4.y + lnb4.y) * (1.0f + gam4.y) + bet4.y);
            p.z = f2bf(((v.z - mu) * rstd * lnw4.z + lnb4.z) * (1.0f + gam4.z) + bet4.z);
            p.w = f2bf(((v.w - mu) * rstd * lnw4.w + lnb4.w) * (1.0f + gam4.w) + bet4.w);
            *(ushort4*)(lds + swzA(t, 4 * l)) = p;
        }
        if (w == 3) {
            ushort4 zp; zp.x = 0; zp.y = 0; zp.z = 0; zp.w = 0;
            *(ushort4*)(lds + swzA(49, 4 * l)) = zp;
        }
    }
    __syncthreads();     // bar1: xm ready

    unsigned oPk[2][2][4][2];    // packed attn-out [hh][dt][it][half]

    #pragma unroll
    for (int hh = 0; hh < 2; ++hh) {
        const int h = 2 * w + hh;

        // ---- Q + K projections (swapped), shared xm B-frags -> qf/kf regs ----
        bf16x8 qf[4], kf[4];
        {
            f32x4 aq[2][4], ak[2][4];
            #pragma unroll
            for (int dt = 0; dt < 2; ++dt)
                #pragma unroll
                for (int tt = 0; tt < 4; ++tt) { aq[dt][tt] = z4; ak[dt][tt] = z4; }
            #pragma unroll
            for (int kt = 0; kt < 8; ++kt) {
                const int ko = kt * 32 + g * 8;
                bf16x8 b0 = *(const bf16x8*)(lds + swzA(c, ko));
                bf16x8 b1 = *(const bf16x8*)(lds + swzA(16 + c, ko));
                bf16x8 b2 = *(const bf16x8*)(lds + swzA(32 + c, ko));
                bf16x8 b3 = z8; if (c < 2) b3 = *(const bf16x8*)(lds + swzA(48 + c, ko));
                bf16x8 wq0 = *(const bf16x8*)(wqb + (h * 32 + c) * 256 + ko);
                bf16x8 wq1 = *(const bf16x8*)(wqb + (h * 32 + 16 + c) * 256 + ko);
                bf16x8 wk0 = *(const bf16x8*)(wkb + (h * 32 + c) * 256 + ko);
                bf16x8 wk1 = *(const bf16x8*)(wkb + (h * 32 + 16 + c) * 256 + ko);
                aq[0][0] = __builtin_amdgcn_mfma_f32_16x16x32_bf16(wq0, b0, aq[0][0], 0, 0, 0);
                aq[0][1] = __builtin_amdgcn_mfma_f32_16x16x32_bf16(wq0, b1, aq[0][1], 0, 0, 0);
                aq[0][2] = __builtin_amdgcn_mfma_f32_16x16x32_bf16(wq0, b2, aq[0][2], 0, 0, 0);
                aq[0][3] = __builtin_amdgcn_mfma_f32_16x16x32_bf16(wq0, b3, aq[0][3], 0, 0, 0);
                aq[1][0] = __builtin_amdgcn_mfma_f32_16x16x32_bf16(wq1, b0, aq[1][0], 0, 0, 0);
                aq[1][1] = __builtin_amdgcn_mfma_f32_16x16x32_bf16(wq1, b1, aq[1][1], 0, 0, 0);
                aq[1][2] = __builtin_amdgcn_mfma_f32_16x16x32_bf16(wq1, b2, aq[1][2], 0, 0, 0);
                aq[1][3] = __builtin_amdgcn_mfma_f32_16x16x32_bf16(wq1, b3, aq[1][3], 0, 0, 0);
                ak[0][0] = __builtin_amdgcn_mfma_f32_16x16x32_bf16(wk0, b0, ak[0][0], 0, 0, 0);
                ak[0][1] = __builtin_amdgcn_mfma_f32_16x16x32_bf16(wk0, b1, ak[0][1], 0, 0, 0);
                ak[0][2] = __builtin_amdgcn_mfma_f32_16x16x32_bf16(wk0, b2, ak[0][2], 0, 0, 0);
                ak[0][3] = __builtin_amdgcn_mfma_f32_16x16x32_bf16(wk0, b3, ak[0][3], 0, 0, 0);
                ak[1][0] = __builtin_amdgcn_mfma_f32_16x16x32_bf16(wk1, b0, ak[1][0], 0, 0, 0);
                ak[1][1] = __builtin_amdgcn_mfma_f32_16x16x32_bf16(wk1, b1, ak[1][1], 0, 0, 0);
                ak[1][2] = __builtin_amdgcn_mfma_f32_16x16x32_bf16(wk1, b2, ak[1][2], 0, 0, 0);
                ak[1][3] = __builtin_amdgcn_mfma_f32_16x16x32_bf16(wk1, b3, ak[1][3], 0, 0, 0);
            }
            unsigned qA[2][4], qB[2][4], kA[2][4], kB[2][4];
            #pragma unroll
            for (int dt = 0; dt < 2; ++dt)
                #pragma unroll
                for (int tt = 0; tt < 4; ++tt) {
                    qA[dt][tt] = pack2(aq[dt][tt][0], aq[dt][tt][1]);
                    qB[dt][tt] = pack2(aq[dt][tt][2], aq[dt][tt][3]);
                    kA[dt][tt] = pack2(ak[dt][tt][0], ak[dt][tt][1]);
                    kB[dt][tt] = pack2(ak[dt][tt][2], ak[dt][tt][3]);
                }
            #pragma unroll
            for (int it = 0; it < 4; ++it) {
                unsigned a0 = (unsigned)__shfl((int)qA[0][it], srcA);
                unsigned a1 = (unsigned)__shfl((int)qA[1][it], srcA);
                unsigned b0 = (unsigned)__shfl((int)qB[0][it], srcA);
                unsigned b1 = (unsigned)__shfl((int)qB[1][it], srcA);
                unsigned c0 = (unsigned)__shfl((int)qA[0][it], srcB);
                unsigned c1 = (unsigned)__shfl((int)qA[1][it], srcB);
                unsigned d0 = (unsigned)__shfl((int)qB[0][it], srcB);
                unsigned d1 = (unsigned)__shfl((int)qB[1][it], srcB);
                qf[it] = build8(hi2 ? a1 : a0, hi2 ? b1 : b0, hi2 ? c1 : c0, hi2 ? d1 : d0);
                a0 = (unsigned)__shfl((int)kA[0][it], srcA);
                a1 = (unsigned)__shfl((int)kA[1][it], srcA);
                b0 = (unsigned)__shfl((int)kB[0][it], srcA);
                b1 = (unsigned)__shfl((int)kB[1][it], srcA);
                c0 = (unsigned)__shfl((int)kA[0][it], srcB);
                c1 = (unsigned)__shfl((int)kA[1][it], srcB);
                d0 = (unsigned)__shfl((int)kB[0][it], srcB);
                d1 = (unsigned)__shfl((int)kB[1][it], srcB);
                kf[it] = build8(hi2 ? a1 : a0, hi2 ? b1 : b0, hi2 ? c1 : c0, hi2 ? d1 : d0);
            }
        }

        // ---- QK^T (swapped, all-reg) + softmax + fused in-reg P redist ----
        bf16x8 pv[4][2];
        #pragma unroll
        for (int it = 0; it < 4; ++it) {
            f32x4 s0 = __builtin_amdgcn_mfma_f32_16x16x32_bf16(kf[0], qf[it], z4, 0, 0, 0);
            f32x4 s1 = __builtin_amdgcn_mfma_f32_16x16x32_bf16(kf[1], qf[it], z4, 0, 0, 0);
            f32x4 s2 = __builtin_amdgcn_mfma_f32_16x16x32_bf16(kf[2], qf[it], z4, 0, 0, 0);
            f32x4 s3 = __builtin_amdgcn_mfma_f32_16x16x32_bf16(kf[3], qf[it], z4, 0, 0, 0);
            const float* bp = bpad + h * 4096 + (it * 16 + c) * 64 + 4 * g;
            float4 B0 = *(const float4*)(bp);
            float4 B1 = *(const float4*)(bp + 16);
            float4 B2 = *(const float4*)(bp + 32);
            float4 B3 = *(const float4*)(bp + 48);
            s0[0] = s0[0] * SCALE_F + B0.x; s0[1] = s0[1] * SCALE_F + B0.y;
            s0[2] = s0[2] * SCALE_F + B0.z; s0[3] = s0[3] * SCALE_F + B0.w;
            s1[0] = s1[0] * SCALE_F + B1.x; s1[1] = s1[1] * SCALE_F + B1.y;
            s1[2] = s1[2] * SCALE_F + B1.z; s1[3] = s1[3] * SCALE_F + B1.w;
            s2[0] = s2[0] * SCALE_F + B2.x; s2[1] = s2[1] * SCALE_F + B2.y;
            s2[2] = s2[2] * SCALE_F + B2.z; s2[3] = s2[3] * SCALE_F + B2.w;
            s3[0] = s3[0] * SCALE_F + B3.x; s3[1] = s3[1] * SCALE_F + B3.y;
            s3[2] = s3[2] * SCALE_F + B3.z; s3[3] = s3[3] * SCALE_F + B3.w;
            float mm = fmaxf(fmaxf(fmaxf(s0[0], s0[1]), fmaxf(s0[2], s0[3])),
                       fmaxf(fmaxf(fmaxf(s1[0], s1[1]), fmaxf(s1[2], s1[3])),
                       fmaxf(fmaxf(fmaxf(s2[0], s2[1]), fmaxf(s2[2], s2[3])),
                             fmaxf(fmaxf(s3[0], s3[1]), fmaxf(s3[2], s3[3])))));
            mm = fmaxf(mm, __shfl_xor(mm, 16));
            mm = fmaxf(mm, __shfl_xor(mm, 32));
            #pragma unroll
            for (int r = 0; r < 4; ++r) {
                s0[r] = exp2f((s0[r] - mm) * LOG2E_F);
                s1[r] = exp2f((s1[r] - mm) * LOG2E_F);
                s2[r] = exp2f((s2[r] - mm) * LOG2E_F);
                s3[r] = exp2f((s3[r] - mm) * LOG2E_F);
            }
            float ss = (s0[0] + s0[1] + s0[2] + s0[3]) + (s1[0] + s1[1] + s1[2] + s1[3])
                     + (s2[0] + s2[1] + s2[2] + s2[3]) + (s3[0] + s3[1] + s3[2] + s3[3]);
            ss += __shfl_xor(ss, 16);
            ss += __shfl_xor(ss, 32);
            float iv = 1.0f / ss;
            #pragma unroll
            for (int r = 0; r < 4; ++r) { s0[r] *= iv; s1[r] *= iv; s2[r] *= iv; s3[r] *= iv; }
            unsigned pkt[4][2];
            pkt[0][0] = pack2(s0[0], s0[1]); pkt[0][1] = pack2(s0[2], s0[3]);
            pkt[1][0] = pack2(s1[0], s1[1]); pkt[1][1] = pack2(s1[2], s1[3]);
            pkt[2][0] = pack2(s2[0], s2[1]); pkt[2][1] = pack2(s2[2], s2[3]);
            pkt[3][0] = pack2(s3[0], s3[1]); pkt[3][1] = pack2(s3[2], s3[3]);
            #pragma unroll
            for (int kt = 0; kt < 2; ++kt) {
                unsigned x0, x1, u0, u1, u2, u3;
                x0 = (unsigned)__shfl((int)pkt[2 * kt][0], srcA);
                x1 = (unsigned)__shfl((int)pkt[2 * kt + 1][0], srcA);
                u0 = hiSel ? x1 : x0;
                x0 = (unsigned)__shfl((int)pkt[2 * kt][1], srcA);
                x1 = (unsigned)__shfl((int)pkt[2 * kt + 1][1], srcA);
                u1 = hiSel ? x1 : x0;
                x0 = (unsigned)__shfl((int)pkt[2 * kt][0], srcB);
                x1 = (unsigned)__shfl((int)pkt[2 * kt + 1][0], srcB);
                u2 = hiSel ? x1 : x0;
                x0 = (unsigned)__shfl((int)pkt[2 * kt][1], srcB);
                x1 = (unsigned)__shfl((int)pkt[2 * kt + 1][1], srcB);
                u3 = hiSel ? x1 : x0;
                pv[it][kt] = build8(u0, u1, u2, u3);
            }
        }

        // ---- V projection (unswapped, shared B-frags) -> va regs ----
        bf16x8 va[2][2];
        {
            f32x4 acc[2][4];
            #pragma unroll
            for (int cti = 0; cti < 2; ++cti)
                #pragma unroll
                for (int tt = 0; tt < 4; ++tt) acc[cti][tt] = z4;
            #pragma unroll
            for (int kt = 0; kt < 8; ++kt) {
                const int ko = kt * 32 + g * 8;
                bf16x8 a0 = *(const bf16x8*)(lds + swzA(c, ko));
                bf16x8 a1 = *(const bf16x8*)(lds + swzA(16 + c, ko));
                bf16x8 a2 = *(const bf16x8*)(lds + swzA(32 + c, ko));
                bf16x8 a3 = z8; if (c < 2) a3 = *(const bf16x8*)(lds + swzA(48 + c, ko));
                bf16x8 b0 = *(const bf16x8*)(wvb + (h * 32 + c) * 256 + ko);
                bf16x8 b1 = *(const bf16x8*)(wvb + (h * 32 + 16 + c) * 256 + ko);
                acc[0][0] = __builtin_amdgcn_mfma_f32_16x16x32_bf16(a0, b0, acc[0][0], 0, 0, 0);
                acc[0][1] = __builtin_amdgcn_mfma_f32_16x16x32_bf16(a1, b0, acc[0][1], 0, 0, 0);
                acc[0][2] = __builtin_amdgcn_mfma_f32_16x16x32_bf16(a2, b0, acc[0][2], 0, 0, 0);
                acc[0][3] = __builtin_amdgcn_mfma_f32_16x16x32_bf16(a3, b0, acc[0][3], 0, 0, 0);
                acc[1][0] = __builtin_amdgcn_mfma_f32_16x16x32_bf16(a0, b1, acc[1][0], 0, 0, 0);
                acc[1][1] = __builtin_amdgcn_mfma_f32_16x16x32_bf16(a1, b1, acc[1][1], 0, 0, 0);
                acc[1][2] = __builtin_amdgcn_mfma_f32_16x16x32_bf16(a2, b1, acc[1][2], 0, 0, 0);
                acc[1][3] = __builtin_amdgcn_mfma_f32_16x16x32_bf16(a3, b1, acc[1][3], 0, 0, 0);
            }
            unsigned vA[2][4], vB[2][4];
            #pragma unroll
            for (int cti = 0; cti < 2; ++cti)
                #pragma unroll
                for (int tt = 0; tt < 4; ++tt) {
                    vA[cti][tt] = pack2(acc[cti][tt][0], acc[cti][tt][1]);
                    vB[cti][tt] = pack2(acc[cti][tt][2], acc[cti][tt][3]);
                }
            #pragma unroll
            for (int dt = 0; dt < 2; ++dt)
                #pragma unroll
                for (int kt = 0; kt < 2; ++kt) {
                    unsigned a0 = (unsigned)__shfl((int)vA[dt][2 * kt],     srcA);
                    unsigned a1 = (unsigned)__shfl((int)vA[dt][2 * kt + 1], srcA);
                    unsigned b0 = (unsigned)__shfl((int)vB[dt][2 * kt],     srcA);
                    unsigned b1 = (unsigned)__shfl((int)vB[dt][2 * kt + 1], srcA);
                    unsigned c0 = (unsigned)__shfl((int)vA[dt][2 * kt],     srcB);
                    unsigned c1 = (unsigned)__shfl((int)vA[dt][2 * kt + 1], srcB);
                    unsigned d0 = (unsigned)__shfl((int)vB[dt][2 * kt],     srcB);
                    unsigned d1 = (unsigned)__shfl((int)vB[dt][2 * kt + 1], srcB);
                    va[dt][kt] = build8(hi2 ? a1 : a0, hi2 ? b1 : b0, hi2 ? c1 : c0, hi2 ? d1 : d0);
                }
        }

        // ---- PV -> packed attn-out regs ----
        #pragma unroll
        for (int dt = 0; dt < 2; ++dt) {
            f32x4 o[4] = {z4, z4, z4, z4};
            #pragma unroll
            for (int kt = 0; kt < 2; ++kt)
                #pragma unroll
                for (int it = 0; it < 4; ++it)
                    o[it] = __builtin_amdgcn_mfma_f32_16x16x32_bf16(va[dt][kt], pv[it][kt], o[it], 0, 0, 0);
            #pragma unroll
            for (int it = 0; it < 4; ++it) {
                oPk[hh][dt][it][0] = pack2(o[it][0], o[it][1]);
                oPk[hh][dt][it][1] = pack2(o[it][2], o[it][3]);
            }
        }
    }
    __syncthreads();     // bar2: all xm reads done -> attn-out may overwrite xm

    // ---- dump packed attn-out -> xm region ----
    #pragma unroll
    for (int hh = 0; hh < 2; ++hh)
        #pragma unroll
        for (int dt = 0; dt < 2; ++dt)
            #pragma unroll
            for (int it = 0; it < 4; ++it)
                if (it < 3 || c < 2) {
                    uint2 u;
                    u.x = oPk[hh][dt][it][0];
                    u.y = oPk[hh][dt][it][1];
                    *(uint2*)(lds + swzA(it * 16 + c, (2 * w + hh) * 32 + dt * 16 + 4 * g)) = u;
                }
    __syncthreads();     // bar3: attn-out ready

    // ---- O projection (swapped, two qp-passes, acc=32) + sigma gate ----
    #pragma unroll
    for (int qp = 0; qp < 2; ++qp) {
        f32x4 acc[2][4];
        #pragma unroll
        for (int qq = 0; qq < 2; ++qq)
            #pragma unroll
            for (int tt = 0; tt < 4; ++tt) acc[qq][tt] = z4;
        #pragma unroll
        for (int kt = 0; kt < 8; ++kt) {
            const int ko = kt * 32 + g * 8;
            bf16x8 b0 = *(const bf16x8*)(lds + swzA(c, ko));
            bf16x8 b1 = *(const bf16x8*)(lds + swzA(16 + c, ko));
            bf16x8 b2 = *(const bf16x8*)(lds + swzA(32 + c, ko));
            bf16x8 b3 = z8; if (c < 2) b3 = *(const bf16x8*)(lds + swzA(48 + c, ko));
            bf16x8 a0 = *(const bf16x8*)(wob + (w * 64 + qp * 32 + c) * 256 + ko);
            bf16x8 a1 = *(const bf16x8*)(wob + (w * 64 + qp * 32 + 16 + c) * 256 + ko);
            acc[0][0] = __builtin_amdgcn_mfma_f32_16x16x32_bf16(a0, b0, acc[0][0], 0, 0, 0);
            acc[0][1] = __builtin_amdgcn_mfma_f32_16x16x32_bf16(a0, b1, acc[0][1], 0, 0, 0);
            acc[0][2] = __builtin_amdgcn_mfma_f32_16x16x32_bf16(a0, b2, acc[0][2], 0, 0, 0);
            acc[0][3] = __builtin_amdgcn_mfma_f32_16x16x32_bf16(a0, b3, acc[0][3], 0, 0, 0);
            acc[1][0] = __builtin_amdgcn_mfma_f32_16x16x32_bf16(a1, b0, acc[1][0], 0, 0, 0);
            acc[1][1] = __builtin_amdgcn_mfma_f32_16x16x32_bf16(a1, b1, acc[1][1], 0, 0, 0);
            acc[1][2] = __builtin_amdgcn_mfma_f32_16x16x32_bf16(a1, b2, acc[1][2], 0, 0, 0);
            acc[1][3] = __builtin_amdgcn_mfma_f32_16x16x32_bf16(a1, b3, acc[1][3], 0, 0, 0);
        }
        #pragma unroll
        for (int qq = 0; qq < 2; ++qq) {
            const int col = w * 64 + qp * 32 + qq * 16 + 4 * g;
            float4 sg = *(const float4*)(gbs + bb * 768 + 512 + col);
            #pragma unroll
            for (int tt = 0; tt < 4; ++tt) {
                int tok = tt * 16 + c;
                if (tok < 49) {
                    float4 o4;
                    o4.x = acc[qq][tt][0] * sg.x;
                    o4.y = acc[qq][tt][1] * sg.y;
                    o4.z = acc[qq][tt][2] * sg.z;
                    o4.w = acc[qq][tt][3] * sg.w;
                    *(float4*)(out + ((size_t)win * 49 + tok) * 256 + col) = o4;
                }
            }
        }
    }
}

extern "C" void kernel_launch(void* const* d_in, const int* in_sizes, int n_in,
                              void* d_out, int out_size, void* d_ws, size_t ws_size,
                              hipStream_t stream) {
    (void)in_sizes; (void)n_in; (void)out_size; (void)ws_size;
    const float* x   = (const float*)d_in[0];
    const float* emb = (const float*)d_in[1];
    const float* lnw = (const float*)d_in[2];
    const float* lnb = (const float*)d_in[3];
    const float* pw  = (const float*)d_in[4];
    const float* wq  = (const float*)d_in[5];
    const float* wk  = (const float*)d_in[6];
    const float* wv  = (const float*)d_in[7];
    const float* wo  = (const float*)d_in[8];
    const float* bt  = (const float*)d_in[9];
    float* out = (float*)d_out;

    char* ws = (char*)d_ws;
    float* gbs = (float*)ws;                                   // 24576 B
    unsigned short* wb = (unsigned short*)(ws + 24576);        // 524288 B
    float* biasp = (float*)(ws + 24576 + 524288);              // 131072 B

    prep_gbs_k<<<24, 256, 0, stream>>>(emb, pw, gbs);
    prep_w_k<<<256, 256, 0, stream>>>(wq, wk, wv, wo, wb);
    prep_bias_k<<<128, 256, 0, stream>>>(bt, biasp);
    attn_main<<<2048, 256, 0, stream>>>(x, lnw, lnb,
                                        wb, wb + 65536, wb + 131072, wb + 196608,
                                        gbs, biasp, out);
}